// Round 7
// baseline (798.899 us; speedup 1.0000x reference)
//
#include <hip/hip_runtime.h>
#include <stdint.h>

typedef _Float16 f16;
typedef f16 half8 __attribute__((ext_vector_type(8)));
typedef f16 half4 __attribute__((ext_vector_type(4)));
typedef float floatx4 __attribute__((ext_vector_type(4)));

#define MFMA_F16(A, B, Cc) __builtin_amdgcn_mfma_f32_16x16x32_f16((A), (B), (Cc), 0, 0, 0)

// Problem constants: B=4, H=W=64 -> N=4096, C=256, d=32
static constexpr int NB  = 4;
static constexpr int NN  = 4096;
static constexpr int NC  = 256;
static constexpr int ND  = 32;
static constexpr int PIX = NB * NN;  // 16384
static constexpr int NS  = 8;        // key splits (grid = 1024 = 4 blocks/CU exact)
static constexpr int KS  = NN / NS;  // 512 keys per split

// Device-global scratch. Fully rewritten every launch.
__device__ __align__(16) f16 g_Xh[(size_t)PIX * NC];        // x as f16
__device__ __align__(16) f16 g_WbT[320 * 256];              // [j][k]
__device__ __align__(16) f16 g_Qh[(size_t)PIX * ND];        // [row][32], pre-scaled log2(e)
__device__ __align__(16) f16 g_Kh[(size_t)PIX * ND];        // [row][32]
__device__ __align__(16) f16 g_VbT[(size_t)NB * NC * NN];   // [b][c][n]
__device__ __align__(16) f16 g_Of[(size_t)NS * PIX * NC];   // per-split normalized O
__device__ float g_m[NS * PIX];                             // per-split max (log2 dom)
__device__ float g_l[NS * PIX];                             // per-split denom

__device__ inline void gl2lds16(const f16* g, f16* l) {
  __builtin_amdgcn_global_load_lds(
      (const __attribute__((address_space(1))) void*)g,
      (__attribute__((address_space(3))) void*)l, 16, 0, 0);
}

// ---------------------------------------------------------------------------
// x fp32 -> f16 (done once; proj re-reads the cheap f16 copy 5x from L2/L3,
// combine uses it for the residual: saves 56 MB of fp32 re-reads)
__global__ __launch_bounds__(256) void prep_x(const float* __restrict__ x) {
  const int t = blockIdx.x * 256 + threadIdx.x;  // 1,048,576 threads x 4 elems
  const floatx4 v = *(const floatx4*)(x + (size_t)t * 4);
  half4 h;
  h[0] = (f16)v[0]; h[1] = (f16)v[1]; h[2] = (f16)v[2]; h[3] = (f16)v[3];
  *(half4*)&g_Xh[(size_t)t * 4] = h;
}

// ---------------------------------------------------------------------------
__global__ __launch_bounds__(256) void prep_weights(const float* __restrict__ wq,
                                                    const float* __restrict__ wk,
                                                    const float* __restrict__ wv) {
  const int tid = blockIdx.x * 256 + threadIdx.x;
  if (tid >= 320 * 256) return;
  const int j = tid >> 8;
  const int k = tid & 255;
  float v;
  if (j < 32)      v = wq[k * 32 + j];
  else if (j < 64) v = wk[k * 32 + (j - 32)];
  else             v = wv[k * 256 + (j - 64)];
  g_WbT[j * 256 + k] = (f16)v;
}

// ---------------------------------------------------------------------------
// QKV projection v2: grid (256 row-tiles x 5 j-chunks), 20 KB LDS.
// blockIdx.y==0 -> Q(32)+K(32); y=1..4 -> V columns (y-1)*64..+64.
// Row strides 40 halfs = 80 B (16B-aligned AND 2-way banks).
__global__ __launch_bounds__(256) void proj_qkv(const float* __restrict__ bq,
                                                const float* __restrict__ bk,
                                                const float* __restrict__ bv) {
  __shared__ f16 xs[64 * 40];   // 5120 B [row][k]
  __shared__ f16 ws[64 * 40];   // 5120 B [j][k]
  __shared__ f16 vt[64 * 80];   // 10240 B [c][row] (stride 80 halfs = 160 B, 16B-mult)

  const int tid  = threadIdx.x;
  const int lane = tid & 63;
  const int wid  = tid >> 6;
  const int qd   = lane >> 4;
  const int c16  = lane & 15;
  const int p0   = blockIdx.x * 64;
  const int y    = blockIdx.y;
  const int jb   = y * 64;
  const floatx4 zero4 = {0.f, 0.f, 0.f, 0.f};

  floatx4 acc[4];
#pragma unroll
  for (int i = 0; i < 4; ++i) acc[i] = zero4;

  for (int kk = 0; kk < 256; kk += 32) {
    {
      const int r = tid >> 2, g3 = tid & 3;
      *(half8*)&xs[r * 40 + g3 * 8] =
          *(const half8*)&g_Xh[(size_t)(p0 + r) * NC + kk + g3 * 8];
      *(half8*)&ws[r * 40 + g3 * 8] =
          *(const half8*)&g_WbT[(size_t)(jb + r) * 256 + kk + g3 * 8];
    }
    __syncthreads();
    const half8 a = *(const half8*)&xs[(wid * 16 + c16) * 40 + qd * 8];
#pragma unroll
    for (int at = 0; at < 4; ++at) {
      const half8 bfr = *(const half8*)&ws[(at * 16 + c16) * 40 + qd * 8];
      acc[at] = MFMA_F16(a, bfr, acc[at]);
    }
    __syncthreads();
  }

  if (y == 0) {
#pragma unroll
    for (int at = 0; at < 4; ++at) {
      const int jj = at * 16 + c16;
      const float bias = (jj < 32) ? bq[jj] : bk[jj - 32];
#pragma unroll
      for (int r = 0; r < 4; ++r) {
        const int p = p0 + wid * 16 + qd * 4 + r;
        const float val = acc[at][r] + bias;
        if (jj < 32) g_Qh[(size_t)p * ND + jj] = (f16)(val * 1.44269504f);
        else         g_Kh[(size_t)p * ND + (jj - 32)] = (f16)val;
      }
    }
  } else {
    const int c0 = (y - 1) * 64;
#pragma unroll
    for (int at = 0; at < 4; ++at) {
      const int c = at * 16 + c16;
      const float bias = bv[c0 + c];
      half4 h;
#pragma unroll
      for (int r = 0; r < 4; ++r) h[r] = (f16)(acc[at][r] + bias);
      *(half4*)&vt[c * 80 + wid * 16 + qd * 4] = h;
    }
    __syncthreads();
    const int b  = p0 >> 12;
    const int n0 = p0 & (NN - 1);
#pragma unroll
    for (int i = 0; i < 2; ++i) {
      const int cid = tid + 256 * i;  // 512 chunks of 8 halfs
      const int c = cid >> 3, m = cid & 7;
      *(half8*)(g_VbT + ((size_t)(b * NC + c0 + c)) * NN + n0 + m * 8) =
          *(const half8*)&vt[c * 80 + m * 8];
    }
  }
}

// ---------------------------------------------------------------------------
// Flash attention: block = 128 q (4 waves x 32 q), K-tile = 64 keys,
// blockIdx.z = 512-key split (NS=8 -> 1024 blocks = 4/CU). LDS 40 KB exact
// (4 x 40 = 160 KB/CU). K direct-from-global regs; V async gl2lds swizzled.
__global__ __launch_bounds__(256, 4) void attn_split(void) {
  __shared__ f16 vsT[256 * 64];     // 32 KB [c][64 keys], chunk-swizzled
  __shared__ f16 ps[4][16 * 64];    //  8 KB [wave][q][64 keys], reused per q-group

  const int tid  = threadIdx.x;
  const int lane = tid & 63;
  const int wid  = tid >> 6;
  const int qd   = lane >> 4;
  const int c16  = lane & 15;
  const int b    = blockIdx.y;
  const int s    = blockIdx.z;
  const int q0   = blockIdx.x * 128 + wid * 32;
  const int sx7  = c16 & 7;
  const floatx4 zero4 = {0.f, 0.f, 0.f, 0.f};

  const int vrow = wid * 64 + (lane >> 3);
  const int vchk = (lane & 7) ^ ((lane >> 3) & 7);
  const f16* vlane = g_VbT + ((size_t)(b * NC + vrow)) * NN + vchk * 8;
  f16* vdst = &vsT[(size_t)wid * 4096];

  half8 qf[2];
#pragma unroll
  for (int g = 0; g < 2; ++g)
    qf[g] = *(const half8*)(g_Qh + ((size_t)(b * NN + q0 + g * 16 + c16)) * ND + qd * 8);

  floatx4 acc[2][16];
#pragma unroll
  for (int g = 0; g < 2; ++g)
#pragma unroll
    for (int i = 0; i < 16; ++i) acc[g][i] = zero4;
  float m_i[2] = {-1e30f, -1e30f};
  float l_p[2] = {0.f, 0.f};

  const int kbeg = s * KS, kend = (s + 1) * KS;

#pragma unroll
  for (int i = 0; i < 8; ++i)
    gl2lds16(vlane + kbeg + i * 8 * NN, vdst + i * 512);
  half8 kreg[4];
#pragma unroll
  for (int a = 0; a < 4; ++a)
    kreg[a] = *(const half8*)(g_Kh + ((size_t)(b * NN + kbeg + a * 16 + c16)) * ND + qd * 8);

  for (int k0 = kbeg; k0 < kend; k0 += 64) {
    // ---- S^T = K * Q^T from registers ----
    floatx4 st[2][4];
#pragma unroll
    for (int g = 0; g < 2; ++g)
#pragma unroll
      for (int a = 0; a < 4; ++a) st[g][a] = MFMA_F16(kreg[a], qf[g], zero4);

    // ---- lazy max (overshoot +5, log2 domain) ----
    float tm[2];
#pragma unroll
    for (int g = 0; g < 2; ++g) {
      float t0 = fmaxf(fmaxf(st[g][0][0], st[g][0][1]), fmaxf(st[g][0][2], st[g][0][3]));
      float t1 = fmaxf(fmaxf(st[g][1][0], st[g][1][1]), fmaxf(st[g][1][2], st[g][1][3]));
      float t2 = fmaxf(fmaxf(st[g][2][0], st[g][2][1]), fmaxf(st[g][2][2], st[g][2][3]));
      float t3 = fmaxf(fmaxf(st[g][3][0], st[g][3][1]), fmaxf(st[g][3][2], st[g][3][3]));
      tm[g] = fmaxf(fmaxf(t0, t1), fmaxf(t2, t3));
    }
    if (__any(tm[0] > m_i[0] || tm[1] > m_i[1])) {
#pragma unroll
      for (int g = 0; g < 2; ++g) {
        float tr = tm[g];
        tr = fmaxf(tr, __shfl_xor(tr, 16));
        tr = fmaxf(tr, __shfl_xor(tr, 32));
        const float m_new = (tr > m_i[g]) ? tr + 5.0f : m_i[g];
        const float alpha = exp2f(m_i[g] - m_new);
        m_i[g] = m_new;
        l_p[g] *= alpha;
        float a4[4];
#pragma unroll
        for (int r = 0; r < 4; ++r) a4[r] = __shfl(alpha, qd * 4 + r);
#pragma unroll
        for (int ct = 0; ct < 16; ++ct)
#pragma unroll
          for (int r = 0; r < 4; ++r) acc[g][ct][r] *= a4[r];
      }
    }

    // ---- P = exp2(s-m); ps buffer reused across the two q-groups (same-wave
    //      DS ops are in-order; fences pin IR ordering only) ----
    half8 pa[2][2];
#pragma unroll
    for (int g = 0; g < 2; ++g) {
      float ts = 0.f;
#pragma unroll
      for (int a = 0; a < 4; ++a) {
        half4 h;
#pragma unroll
        for (int r = 0; r < 4; ++r) {
          const float p = exp2f(st[g][a][r] - m_i[g]);
          ts += p;
          h[r] = (f16)p;
        }
        const int pc = ((a * 2 + (qd >> 1)) ^ sx7) * 8 + (qd & 1) * 4;
        *(half4*)&ps[wid][c16 * 64 + pc] = h;
      }
      l_p[g] += ts;
      asm volatile("" ::: "memory");
#pragma unroll
      for (int kh = 0; kh < 2; ++kh)
        pa[g][kh] = *(const half8*)&ps[wid][c16 * 64 + ((kh * 4 + qd) ^ sx7) * 8];
      asm volatile("" ::: "memory");
    }

    __syncthreads();  // [A] drains vmcnt -> vsT(k0) landed everywhere

    // ---- prefetch K(next) into regs ----
    const int k0n = (k0 + 64 < kend) ? (k0 + 64) : kbeg;
    half8 knew[4];
#pragma unroll
    for (int a = 0; a < 4; ++a)
      knew[a] = *(const half8*)(g_Kh + ((size_t)(b * NN + k0n + a * 16 + c16)) * ND + qd * 8);

    // ---- PV: O += P * V, 64 MFMAs ----
#pragma unroll
    for (int ct = 0; ct < 16; ++ct) {
#pragma unroll
      for (int kh = 0; kh < 2; ++kh) {
        const half8 bfr =
            *(const half8*)&vsT[(ct * 16 + c16) * 64 + ((kh * 4 + qd) ^ sx7) * 8];
        acc[0][ct] = MFMA_F16(pa[0][kh], bfr, acc[0][ct]);
        acc[1][ct] = MFMA_F16(pa[1][kh], bfr, acc[1][ct]);
      }
    }
    __syncthreads();  // [B] all waves done reading vsT(k0)

    if (k0 + 64 < kend) {
#pragma unroll
      for (int i = 0; i < 8; ++i)
        gl2lds16(vlane + (k0 + 64) + i * 8 * NN, vdst + i * 512);
    }
#pragma unroll
    for (int a = 0; a < 4; ++a) kreg[a] = knew[a];
  }

  // ---- epilogue ----
#pragma unroll
  for (int g = 0; g < 2; ++g) {
    float l = l_p[g];
    l += __shfl_xor(l, 16);
    l += __shfl_xor(l, 32);
    if (qd == 0) {
      const int row = b * NN + q0 + g * 16 + c16;
      g_m[s * PIX + row] = m_i[g];
      g_l[s * PIX + row] = l;
    }
    float linv[4];
#pragma unroll
    for (int r = 0; r < 4; ++r) linv[r] = 1.0f / __shfl(l, qd * 4 + r);
#pragma unroll
    for (int ct = 0; ct < 16; ++ct)
#pragma unroll
      for (int r = 0; r < 4; ++r) {
        const int qrow = q0 + g * 16 + qd * 4 + r;
        const int c = ct * 16 + c16;
        g_Of[((size_t)(s * PIX + b * NN + qrow)) * NC + c] = (f16)(acc[g][ct][r] * linv[r]);
      }
  }
}

// ---------------------------------------------------------------------------
// Merge NS partials (log2 domain); residual from g_Xh (f16).
__global__ __launch_bounds__(256) void combine(float* __restrict__ out) {
  const int tid  = threadIdx.x;
  const int lane = tid & 63;
  const int wid  = tid >> 6;
  const int row  = blockIdx.x * 4 + wid;
  const int c    = lane * 4;

  float m[NS], l[NS], M = -1e30f;
#pragma unroll
  for (int s = 0; s < NS; ++s) {
    m[s] = g_m[s * PIX + row];
    l[s] = g_l[s * PIX + row];
    M = fmaxf(M, m[s]);
  }
  float w[NS], den = 0.f;
#pragma unroll
  for (int s = 0; s < NS; ++s) { w[s] = l[s] * exp2f(m[s] - M); den += w[s]; }
  const float inv = 1.0f / den;

  float a0 = 0.f, a1 = 0.f, a2 = 0.f, a3 = 0.f;
#pragma unroll
  for (int s = 0; s < NS; ++s) {
    const half4 h = *(const half4*)&g_Of[((size_t)(s * PIX + row)) * NC + c];
    const float ws = w[s] * inv;
    a0 += ws * (float)h[0];
    a1 += ws * (float)h[1];
    a2 += ws * (float)h[2];
    a3 += ws * (float)h[3];
  }
  const half4 xv = *(const half4*)&g_Xh[(size_t)row * NC + c];
  floatx4 o;
  o[0] = a0 + (float)xv[0]; o[1] = a1 + (float)xv[1];
  o[2] = a2 + (float)xv[2]; o[3] = a3 + (float)xv[3];
  *(floatx4*)&out[(size_t)row * NC + c] = o;
}

// ---------------------------------------------------------------------------
extern "C" void kernel_launch(void* const* d_in, const int* in_sizes, int n_in,
                              void* d_out, int out_size, void* d_ws, size_t ws_size,
                              hipStream_t stream) {
  (void)in_sizes; (void)n_in; (void)d_ws; (void)ws_size; (void)out_size;
  const float* x  = (const float*)d_in[0];
  const float* wq = (const float*)d_in[1];
  const float* bq = (const float*)d_in[2];
  const float* wk = (const float*)d_in[3];
  const float* bk = (const float*)d_in[4];
  const float* wv = (const float*)d_in[5];
  const float* bv = (const float*)d_in[6];
  float* out = (float*)d_out;

  hipLaunchKernelGGL(prep_x, dim3(PIX * NC / 1024), dim3(256), 0, stream, x);
  hipLaunchKernelGGL(prep_weights, dim3(320), dim3(256), 0, stream, wq, wk, wv);
  hipLaunchKernelGGL(proj_qkv, dim3(256, 5), dim3(256), 0, stream, bq, bk, bv);
  hipLaunchKernelGGL(attn_split, dim3(NN / 128, NB, NS), dim3(256), 0, stream);
  hipLaunchKernelGGL(combine, dim3(PIX / 4), dim3(256), 0, stream, out);
}

// Round 8
// 171.014 us; speedup vs baseline: 4.6716x; 4.6716x over previous
//
#include <hip/hip_runtime.h>
#include <stdint.h>

typedef _Float16 f16;
typedef f16 half8 __attribute__((ext_vector_type(8)));
typedef f16 half4 __attribute__((ext_vector_type(4)));
typedef float floatx4 __attribute__((ext_vector_type(4)));

#define MFMA_F16(A, B, Cc) __builtin_amdgcn_mfma_f32_16x16x32_f16((A), (B), (Cc), 0, 0, 0)

// Problem constants: B=4, H=W=64 -> N=4096, C=256, d=32
static constexpr int NB  = 4;
static constexpr int NN  = 4096;
static constexpr int NC  = 256;
static constexpr int ND  = 32;
static constexpr int PIX = NB * NN;  // 16384
static constexpr int NS  = 4;        // key splits (grid 512 = 2 blocks/CU, the reg-pressure cap)
static constexpr int KS  = NN / NS;  // 1024 keys per split

// Device-global scratch. Fully rewritten every launch.
__device__ __align__(16) f16 g_Xh[(size_t)PIX * NC];        // x as f16
__device__ __align__(16) f16 g_WbT[320 * 256];              // [j][k]
__device__ __align__(16) f16 g_Qh[(size_t)PIX * ND];        // [row][32], pre-scaled log2(e)
__device__ __align__(16) f16 g_Kh[(size_t)PIX * ND];        // [row][32]
__device__ __align__(16) f16 g_VbT[(size_t)NB * NC * NN];   // [b][c][n]
__device__ __align__(16) f16 g_Of[(size_t)NS * PIX * NC];   // per-split normalized O
__device__ float g_m[NS * PIX];                             // per-split max (log2 dom)
__device__ float g_l[NS * PIX];                             // per-split denom

__device__ inline void gl2lds16(const f16* g, f16* l) {
  __builtin_amdgcn_global_load_lds(
      (const __attribute__((address_space(1))) void*)g,
      (__attribute__((address_space(3))) void*)l, 16, 0, 0);
}

// ---------------------------------------------------------------------------
__global__ __launch_bounds__(256) void prep_x(const float* __restrict__ x) {
  const int t = blockIdx.x * 256 + threadIdx.x;
  const floatx4 v = *(const floatx4*)(x + (size_t)t * 4);
  half4 h;
  h[0] = (f16)v[0]; h[1] = (f16)v[1]; h[2] = (f16)v[2]; h[3] = (f16)v[3];
  *(half4*)&g_Xh[(size_t)t * 4] = h;
}

// ---------------------------------------------------------------------------
__global__ __launch_bounds__(256) void prep_weights(const float* __restrict__ wq,
                                                    const float* __restrict__ wk,
                                                    const float* __restrict__ wv) {
  const int tid = blockIdx.x * 256 + threadIdx.x;
  if (tid >= 320 * 256) return;
  const int j = tid >> 8;
  const int k = tid & 255;
  float v;
  if (j < 32)      v = wq[k * 32 + j];
  else if (j < 64) v = wk[k * 32 + (j - 32)];
  else             v = wv[k * 256 + (j - 64)];
  g_WbT[j * 256 + k] = (f16)v;
}

// ---------------------------------------------------------------------------
// QKV projection (round-7 v2, passed): grid (256 row-tiles x 5 j-chunks).
__global__ __launch_bounds__(256) void proj_qkv(const float* __restrict__ bq,
                                                const float* __restrict__ bk,
                                                const float* __restrict__ bv) {
  __shared__ f16 xs[64 * 40];
  __shared__ f16 ws[64 * 40];
  __shared__ f16 vt[64 * 80];

  const int tid  = threadIdx.x;
  const int lane = tid & 63;
  const int wid  = tid >> 6;
  const int qd   = lane >> 4;
  const int c16  = lane & 15;
  const int p0   = blockIdx.x * 64;
  const int y    = blockIdx.y;
  const int jb   = y * 64;
  const floatx4 zero4 = {0.f, 0.f, 0.f, 0.f};

  floatx4 acc[4];
#pragma unroll
  for (int i = 0; i < 4; ++i) acc[i] = zero4;

  for (int kk = 0; kk < 256; kk += 32) {
    {
      const int r = tid >> 2, g3 = tid & 3;
      *(half8*)&xs[r * 40 + g3 * 8] =
          *(const half8*)&g_Xh[(size_t)(p0 + r) * NC + kk + g3 * 8];
      *(half8*)&ws[r * 40 + g3 * 8] =
          *(const half8*)&g_WbT[(size_t)(jb + r) * 256 + kk + g3 * 8];
    }
    __syncthreads();
    const half8 a = *(const half8*)&xs[(wid * 16 + c16) * 40 + qd * 8];
#pragma unroll
    for (int at = 0; at < 4; ++at) {
      const half8 bfr = *(const half8*)&ws[(at * 16 + c16) * 40 + qd * 8];
      acc[at] = MFMA_F16(a, bfr, acc[at]);
    }
    __syncthreads();
  }

  if (y == 0) {
#pragma unroll
    for (int at = 0; at < 4; ++at) {
      const int jj = at * 16 + c16;
      const float bias = (jj < 32) ? bq[jj] : bk[jj - 32];
#pragma unroll
      for (int r = 0; r < 4; ++r) {
        const int p = p0 + wid * 16 + qd * 4 + r;
        const float val = acc[at][r] + bias;
        if (jj < 32) g_Qh[(size_t)p * ND + jj] = (f16)(val * 1.44269504f);
        else         g_Kh[(size_t)p * ND + (jj - 32)] = (f16)val;
      }
    }
  } else {
    const int c0 = (y - 1) * 64;
#pragma unroll
    for (int at = 0; at < 4; ++at) {
      const int c = at * 16 + c16;
      const float bias = bv[c0 + c];
      half4 h;
#pragma unroll
      for (int r = 0; r < 4; ++r) h[r] = (f16)(acc[at][r] + bias);
      *(half4*)&vt[c * 80 + wid * 16 + qd * 4] = h;
    }
    __syncthreads();
    const int b  = p0 >> 12;
    const int n0 = p0 & (NN - 1);
#pragma unroll
    for (int i = 0; i < 2; ++i) {
      const int cid = tid + 256 * i;
      const int c = cid >> 3, m = cid & 7;
      *(half8*)(g_VbT + ((size_t)(b * NC + c0 + c)) * NN + n0 + m * 8) =
          *(const half8*)&vt[c * 80 + m * 8];
    }
  }
}

// ---------------------------------------------------------------------------
// Flash attention v3: block = 128 q (4 waves x 32 q), K-step = 32 keys,
// vsT double-buffered -> ONE barrier per step; V(k+1) issued at step top so
// its in-flight window is the whole step. ps is per-wave (no barrier).
// LDS rows = 32 keys = 4x16B chunks; physical chunk = logical ^ ((row>>1)&3)
// (reads 2-way bank aliased = free). 36 KB LDS, 2 blocks/CU (reg-capped:
// acc[2][16]x4 = 128 f32/lane; do NOT force occupancy via launch_bounds —
// round 7's (256,4) forced 64 VGPRs -> spill to scratch -> 3.5 GB HBM).
__global__ __launch_bounds__(256, 2) void attn_split(void) {
  __shared__ f16 vsT[2][256 * 32];   // 32 KB dbuf [c][32 keys]
  __shared__ f16 ps[4][16 * 32];     //  4 KB [wave][q][32 keys]

  const int tid  = threadIdx.x;
  const int lane = tid & 63;
  const int wid  = tid >> 6;
  const int qd   = lane >> 4;
  const int c16  = lane & 15;
  const int b    = blockIdx.y;
  const int s    = blockIdx.z;
  const int q0   = blockIdx.x * 128 + wid * 32;
  const int swz  = (c16 >> 1) & 3;
  const floatx4 zero4 = {0.f, 0.f, 0.f, 0.f};

  // V staging: wave stages channels [wid*64, wid*64+64) x 32 keys, 4 instrs.
  // Dest slot (lane-linear) row = j*16 + (lane>>2), pchunk = lane&3;
  // source chunk = pchunk ^ ((row>>1)&3) = (lane&3) ^ ((lane>>3)&3).
  const int vr = wid * 64 + (lane >> 2);
  const int vc = (lane & 3) ^ ((lane >> 3) & 3);
  const f16* vlane = g_VbT + ((size_t)(b * NC + vr)) * NN + vc * 8;

  half8 qf[2];
#pragma unroll
  for (int g = 0; g < 2; ++g)
    qf[g] = *(const half8*)(g_Qh + ((size_t)(b * NN + q0 + g * 16 + c16)) * ND + qd * 8);

  floatx4 acc[2][16];
#pragma unroll
  for (int g = 0; g < 2; ++g)
#pragma unroll
    for (int i = 0; i < 16; ++i) acc[g][i] = zero4;
  float m_i[2] = {-1e30f, -1e30f};
  float l_p[2] = {0.f, 0.f};

  const int kbeg = s * KS;
  const int nst  = KS / 32;  // 32 steps

  // prologue: V(step 0) -> buf0; K(step 0) -> regs
#pragma unroll
  for (int j = 0; j < 4; ++j)
    gl2lds16(vlane + kbeg + j * 16 * NN, &vsT[0][wid * 2048 + j * 512]);
  half8 kreg[2];
#pragma unroll
  for (int a = 0; a < 2; ++a)
    kreg[a] = *(const half8*)(g_Kh + ((size_t)(b * NN + kbeg + a * 16 + c16)) * ND + qd * 8);

  for (int it = 0; it < nst; ++it) {
    const int k0 = kbeg + it * 32;
    __syncthreads();  // drains vmcnt: V(it) landed; all waves done with PV(it-1)

    // issue V(it+1) into the other buffer — in flight for the whole step
    if (it + 1 < nst) {
      f16* vd = &vsT[(it + 1) & 1][wid * 2048];
#pragma unroll
      for (int j = 0; j < 4; ++j)
        gl2lds16(vlane + (k0 + 32) + j * 16 * NN, vd + j * 512);
    }
    // K prefetch for next step (global -> regs, full-step window)
    const int k0n = (it + 1 < nst) ? k0 + 32 : kbeg;
    half8 knew[2];
#pragma unroll
    for (int a = 0; a < 2; ++a)
      knew[a] = *(const half8*)(g_Kh + ((size_t)(b * NN + k0n + a * 16 + c16)) * ND + qd * 8);

    // ---- S^T = K * Q^T : 4 MFMAs (2 key-atiles x 2 q-groups) ----
    floatx4 st[2][2];
#pragma unroll
    for (int g = 0; g < 2; ++g)
#pragma unroll
      for (int a = 0; a < 2; ++a) st[g][a] = MFMA_F16(kreg[a], qf[g], zero4);

    // ---- lazy max (overshoot +5, log2 domain) ----
    float tm[2];
#pragma unroll
    for (int g = 0; g < 2; ++g) {
      float t0 = fmaxf(fmaxf(st[g][0][0], st[g][0][1]), fmaxf(st[g][0][2], st[g][0][3]));
      float t1 = fmaxf(fmaxf(st[g][1][0], st[g][1][1]), fmaxf(st[g][1][2], st[g][1][3]));
      tm[g] = fmaxf(t0, t1);
    }
    if (__any(tm[0] > m_i[0] || tm[1] > m_i[1])) {
#pragma unroll
      for (int g = 0; g < 2; ++g) {
        float tr = tm[g];
        tr = fmaxf(tr, __shfl_xor(tr, 16));
        tr = fmaxf(tr, __shfl_xor(tr, 32));
        const float m_new = (tr > m_i[g]) ? tr + 5.0f : m_i[g];
        const float alpha = exp2f(m_i[g] - m_new);
        m_i[g] = m_new;
        l_p[g] *= alpha;
        float a4[4];
#pragma unroll
        for (int r = 0; r < 4; ++r) a4[r] = __shfl(alpha, qd * 4 + r);
#pragma unroll
        for (int ct = 0; ct < 16; ++ct)
#pragma unroll
          for (int r = 0; r < 4; ++r) acc[g][ct][r] *= a4[r];
      }
    }

    // ---- P = exp2(s-m) -> ps (swizzled, per-wave) -> A-frags ----
    half8 pa[2];
#pragma unroll
    for (int g = 0; g < 2; ++g) {
      float ts = 0.f;
#pragma unroll
      for (int a = 0; a < 2; ++a) {
        half4 h;
#pragma unroll
        for (int r = 0; r < 4; ++r) {
          const float p = exp2f(st[g][a][r] - m_i[g]);
          ts += p;
          h[r] = (f16)p;
        }
        const int pc = (a * 2 + (qd >> 1)) ^ swz;
        *(half4*)&ps[wid][c16 * 32 + pc * 8 + (qd & 1) * 4] = h;
      }
      l_p[g] += ts;
      asm volatile("" ::: "memory");
      pa[g] = *(const half8*)&ps[wid][c16 * 32 + (qd ^ swz) * 8];
      asm volatile("" ::: "memory");
    }

    // ---- PV: O += P * V, 32 MFMAs from vsT[it&1] ----
    const f16* vb = &vsT[it & 1][0];
    const int vchunk = (qd ^ swz) * 8;
#pragma unroll
    for (int ct = 0; ct < 16; ++ct) {
      const half8 bfr = *(const half8*)&vb[(ct * 16 + c16) * 32 + vchunk];
      acc[0][ct] = MFMA_F16(pa[0], bfr, acc[0][ct]);
      acc[1][ct] = MFMA_F16(pa[1], bfr, acc[1][ct]);
    }
#pragma unroll
    for (int a = 0; a < 2; ++a) kreg[a] = knew[a];
  }

  // ---- epilogue ----
#pragma unroll
  for (int g = 0; g < 2; ++g) {
    float l = l_p[g];
    l += __shfl_xor(l, 16);
    l += __shfl_xor(l, 32);
    if (qd == 0) {
      const int row = b * NN + q0 + g * 16 + c16;
      g_m[s * PIX + row] = m_i[g];
      g_l[s * PIX + row] = l;
    }
    float linv[4];
#pragma unroll
    for (int r = 0; r < 4; ++r) linv[r] = 1.0f / __shfl(l, qd * 4 + r);
#pragma unroll
    for (int ct = 0; ct < 16; ++ct)
#pragma unroll
      for (int r = 0; r < 4; ++r) {
        const int qrow = q0 + g * 16 + qd * 4 + r;
        const int c = ct * 16 + c16;
        g_Of[((size_t)(s * PIX + b * NN + qrow)) * NC + c] = (f16)(acc[g][ct][r] * linv[r]);
      }
  }
}

// ---------------------------------------------------------------------------
// Merge NS partials (log2 domain); residual from g_Xh (f16).
__global__ __launch_bounds__(256) void combine(float* __restrict__ out) {
  const int tid  = threadIdx.x;
  const int lane = tid & 63;
  const int wid  = tid >> 6;
  const int row  = blockIdx.x * 4 + wid;
  const int c    = lane * 4;

  float m[NS], l[NS], M = -1e30f;
#pragma unroll
  for (int s = 0; s < NS; ++s) {
    m[s] = g_m[s * PIX + row];
    l[s] = g_l[s * PIX + row];
    M = fmaxf(M, m[s]);
  }
  float w[NS], den = 0.f;
#pragma unroll
  for (int s = 0; s < NS; ++s) { w[s] = l[s] * exp2f(m[s] - M); den += w[s]; }
  const float inv = 1.0f / den;

  float a0 = 0.f, a1 = 0.f, a2 = 0.f, a3 = 0.f;
#pragma unroll
  for (int s = 0; s < NS; ++s) {
    const half4 h = *(const half4*)&g_Of[((size_t)(s * PIX + row)) * NC + c];
    const float ws = w[s] * inv;
    a0 += ws * (float)h[0];
    a1 += ws * (float)h[1];
    a2 += ws * (float)h[2];
    a3 += ws * (float)h[3];
  }
  const half4 xv = *(const half4*)&g_Xh[(size_t)row * NC + c];
  floatx4 o;
  o[0] = a0 + (float)xv[0]; o[1] = a1 + (float)xv[1];
  o[2] = a2 + (float)xv[2]; o[3] = a3 + (float)xv[3];
  *(floatx4*)&out[(size_t)row * NC + c] = o;
}

// ---------------------------------------------------------------------------
extern "C" void kernel_launch(void* const* d_in, const int* in_sizes, int n_in,
                              void* d_out, int out_size, void* d_ws, size_t ws_size,
                              hipStream_t stream) {
  (void)in_sizes; (void)n_in; (void)d_ws; (void)ws_size; (void)out_size;
  const float* x  = (const float*)d_in[0];
  const float* wq = (const float*)d_in[1];
  const float* bq = (const float*)d_in[2];
  const float* wk = (const float*)d_in[3];
  const float* bk = (const float*)d_in[4];
  const float* wv = (const float*)d_in[5];
  const float* bv = (const float*)d_in[6];
  float* out = (float*)d_out;

  hipLaunchKernelGGL(prep_x, dim3(PIX * NC / 1024), dim3(256), 0, stream, x);
  hipLaunchKernelGGL(prep_weights, dim3(320), dim3(256), 0, stream, wq, wk, wv);
  hipLaunchKernelGGL(proj_qkv, dim3(256, 5), dim3(256), 0, stream, bq, bk, bv);
  hipLaunchKernelGGL(attn_split, dim3(NN / 128, NB, NS), dim3(256), 0, stream);
  hipLaunchKernelGGL(combine, dim3(PIX / 4), dim3(256), 0, stream, out);
}